// Round 6
// baseline (676.562 us; speedup 1.0000x reference)
//
#include <hip/hip_runtime.h>
#include <hip/hip_bf16.h>
#include <hip/hip_fp16.h>

// Problem dims
#define A_DIM 4608   // C*9 patch-feature rows
#define L_DIM 4096   // (H/3)*(W/3) spatial columns
#define CH    512
#define H_DIM 192
#define W_DIM 192

// GEMM tile: 128x192, 64x96 wave tile (R2-proven). R13: BK=16, TRIPLE buffer
// (3 x 20 KB = 60 KB, 2 blocks/CU), ONE barrier per K-step, 2-deep prefetch.
#define BM 128
#define BN 192
#define BK 16        // 2 kchunks of 8 halves per stage
#define NS (L_DIM / BK)

#define CPB 32       // prep: channels per block

typedef _Float16 half8 __attribute__((ext_vector_type(8)));
typedef float   floatx4 __attribute__((ext_vector_type(4)));
typedef float   floatx16 __attribute__((ext_vector_type(16)));

// ---------------------------------------------------------------------------
// Pass 1: unfold(x) -> k-chunk-major f16 hi/lo split + global sum-of-squares
// accumulation (ss arrays pre-zeroed). 8-lane shuffle reduce + one global
// atomic per (c_l, q).
// Global layout: U[(l>>3)*A_DIM + a][8] (chunk-major; GEMM staging contiguous
// and conflict-free — verified: GEMM SQ_LDS_BANK_CONFLICT = 0).
// ---------------------------------------------------------------------------
__global__ __launch_bounds__(256) void prep_kernel(
    const float* __restrict__ x0, const float* __restrict__ x1,
    _Float16* __restrict__ Uhi0, _Float16* __restrict__ Ulo0,
    _Float16* __restrict__ Uhi1, _Float16* __restrict__ Ulo1,
    float* __restrict__ ss0, float* __restrict__ ss1) {
  const int which = blockIdx.z;
  const float* __restrict__ x = which ? x1 : x0;
  _Float16* __restrict__ Uhi = which ? Uhi1 : Uhi0;
  _Float16* __restrict__ Ulo = which ? Ulo1 : Ulo0;
  float* __restrict__ ssg = which ? ss1 : ss0;

  const int ph = blockIdx.y;            // 0..63
  const int c0 = blockIdx.x * CPB;      // channel group base
  const int abase = blockIdx.x * (CPB * 9);

  __shared__ _Float16 sHi[CPB * 9 * 8 * 8];  // 288 rows x 8 chunks x 8 halves
  __shared__ _Float16 sLo[CPB * 9 * 8 * 8];

  const int t = threadIdx.x;

  // ---- phase 1: read input, assemble 16B chunks in regs, stage in LDS
  const int c_l = t >> 3;               // 0..31
  const int s = t & 7;                  // chunk index this thread owns
  const float* __restrict__ rowbase =
      x + ((size_t)(c0 + c_l) * H_DIM + 3 * ph) * W_DIM + s * 24;
  float ssp[9] = {0.f, 0.f, 0.f, 0.f, 0.f, 0.f, 0.f, 0.f, 0.f};

#pragma unroll
  for (int kh = 0; kh < 3; ++kh) {
    const float* __restrict__ rp = rowbase + kh * W_DIM;
    floatx4 v4[6];
#pragma unroll
    for (int i = 0; i < 6; ++i) v4[i] = *(const floatx4*)(rp + i * 4);
    half8 hv[3], lv[3];
#pragma unroll
    for (int i = 0; i < 6; ++i)
#pragma unroll
      for (int j = 0; j < 4; ++j) {
        const int m = i * 4 + j;        // 0..23
        const int kw = m % 3, e = m / 3;
        const float v = v4[i][j];
        ssp[kh * 3 + kw] += v * v;
        const _Float16 h = (_Float16)v;
        hv[kw][e] = h;
        lv[kw][e] = (_Float16)(v - (float)h);
      }
#pragma unroll
    for (int kw = 0; kw < 3; ++kw) {
      const int a_l = c_l * 9 + kh * 3 + kw;
      const int addr = (a_l * 8 + (s ^ (a_l & 7))) * 8;  // XOR-swizzled chunk
      *(half8*)&sHi[addr] = hv[kw];
      *(half8*)&sLo[addr] = lv[kw];
    }
  }
  // ---- norm accumulation: 8-lane shuffle reduce over s, one global atomic
#pragma unroll
  for (int q = 0; q < 9; ++q) {
    float v = ssp[q];
    v += __shfl_down(v, 4, 8);
    v += __shfl_down(v, 2, 8);
    v += __shfl_down(v, 1, 8);
    if (s == 0) atomicAdd(&ssg[abase + c_l * 9 + q], v);
  }
  __syncthreads();

  // ---- phase 2: coalesced global writes (consecutive t = consecutive a)
#pragma unroll
  for (int i = 0; i < 9; ++i) {
    const int idx = i * 256 + t;        // 0..2303
    const int c8 = idx / 288;
    const int a_l = idx - c8 * 288;
    const int addr = (a_l * 8 + (c8 ^ (a_l & 7))) * 8;
    const size_t g = ((size_t)(ph * 8 + c8) * A_DIM + abase + a_l) * 8;
    *(half8*)&Uhi[g] = *(const half8*)&sHi[addr];
    *(half8*)&Ulo[g] = *(const half8*)&sLo[addr];
  }
}

// ---------------------------------------------------------------------------
// Pass 2: D[i,j] = sty_i . img_j, 3-term f16 split, 32x32x16 MFMA, 128x192
// tile.
//
// R13: every barrier-bounded schedule (R2/R4/R5, 2- and 3-phase, 2 and 4
// blocks/CU) pinned at 49-54% MfmaUtil: LDS-reads and MFMAs serialize
// because the post-compute barrier re-converges all waves every K-step.
// This version: TRIPLE buffer, ONE barrier per K-step:
//   vmcnt(5)   -- my stage-ks GLDS done (leaves stage ks+1's 5 in flight;
//                 queue never drains in the main loop)
//   s_barrier  -- everyone's stage-ks done AND everyone done reading ks-1
//   ISSUE(buf[(ks+2)%3], stage ks+2)   -- overwrites buf last read at ks-1
//   compute(buf[ks%3])  -- 10 ds_read_b128 + 18 MFMA, compiler-scheduled,
//                          NO trailing barrier: wave skew lets one wave's
//                          reads overlap another's MFMAs.
// Safety: a wave's ds_reads complete before its consuming MFMAs issue
// (compiler lgkmcnt), hence before it reaches the next step's barrier.
// Per-acc-element accumulation order (kchunk pairs ascending, terms
// hh,hl,lh) identical to R2 -> bit-identical output.
//
// Block swizzle (1-D grid, 864 = 3*288 blocks): id -> (bx,by); XCD
// (heuristic id%8) pins one B col-tile (3 MB, fits 4 MB XCD-L2) across all
// 36 by-steps.
// ---------------------------------------------------------------------------
#define GLDS(g, l)                                                          \
  __builtin_amdgcn_global_load_lds(                                        \
      (const __attribute__((address_space(1))) void*)(g),                   \
      (__attribute__((address_space(3))) void*)(l), 16, 0, 0)

#define MFMA_(A, B, C) __builtin_amdgcn_mfma_f32_32x32x16_f16(A, B, C, 0, 0, 0)

// Buffer layout (halves, per 10240-half buffer):
//   Ah [0,2048)  Al [2048,4096)  Bh [4096,7168)  Bl [7168,10240)
// A: 2 kc x 128 rows x 8; B: 2 kc x 192 rows x 8.
__global__ __launch_bounds__(256, 2) void gemm_max_kernel(
    const _Float16* __restrict__ Shi, const _Float16* __restrict__ Slo,
    const _Float16* __restrict__ Ihi, const _Float16* __restrict__ Ilo,
    const float* __restrict__ img_ss,
    unsigned long long* __restrict__ packed) {
  __shared__ _Float16 sm[3 * 10240];  // 60 KB -> 2 blocks/CU

  const int t = threadIdx.x;
  const int lane = t & 63, wv = t >> 6;
  const int wvr = wv >> 1, wvc = wv & 1;       // 2x2 waves, wave tile 64x96
  const int id = blockIdx.x;
  const int g = id / 288, r = id - g * 288;
  const int by = r >> 3, bx = g * 8 + (r & 7);
  const int row0 = by * BM;                    // sty rows (i)
  const int col0 = bx * BN;                    // img rows (j)
  const int l31 = lane & 31, hs = lane >> 5;

  floatx16 acc[2][3];
#pragma unroll
  for (int rf = 0; rf < 2; ++rf)
#pragma unroll
    for (int cf = 0; cf < 3; ++cf) acc[rf][cf] = (floatx16)0.f;

  const size_t CH8 = (size_t)A_DIM * 8;        // one kchunk plane, in halves

  // ---- staging decomposition (all per-thread constants, wave-contiguous
  // LDS dests as required by global_load_lds)
  // A: thread t -> (kc = t>>7, row = t&127), 1 GLDS each for Ah, Al.
  const size_t aOff = (size_t)(t >> 7) * CH8 + (size_t)(row0 + (t & 127)) * 8;
  const int aDst = t * 8;
  // B: 768 chunks (2 mats x 2 kc x 192 rows) = 3 per thread, c = i*256 + t.
  // i=0: mat 0, rem = t
  const size_t bG0 =
      (size_t)(t / 192) * CH8 + (size_t)(col0 + (t % 192)) * 8;
  const int bD0 = 4096 + t * 8;
  // i=1: c = 256+t, mat = (c>=384), rem = c - mat*384  (mat uniform per wave)
  const int c1 = 256 + t;
  const int mat1 = (c1 >= 384) ? 1 : 0;
  const int rem1 = c1 - mat1 * 384;
  const _Float16* __restrict__ bP1 = mat1 ? Ilo : Ihi;
  const size_t bG1 =
      (size_t)(rem1 / 192) * CH8 + (size_t)(col0 + (rem1 % 192)) * 8;
  const int bD1 = 4096 + mat1 * 3072 + rem1 * 8;
  // i=2: c = 512+t, mat 1, rem = 128+t
  const int rem2 = 128 + t;
  const size_t bG2 =
      (size_t)(rem2 / 192) * CH8 + (size_t)(col0 + (rem2 % 192)) * 8;
  const int bD2 = 7168 + rem2 * 8;

#define ISSUE(BB, koff)                                  \
  do {                                                   \
    GLDS(Shi + (koff) + aOff, &sm[(BB) + aDst]);         \
    GLDS(Slo + (koff) + aOff, &sm[(BB) + 2048 + aDst]);  \
    GLDS(Ihi + (koff) + bG0, &sm[(BB) + bD0]);           \
    GLDS(bP1 + (koff) + bG1, &sm[(BB) + bD1]);           \
    GLDS(Ilo + (koff) + bG2, &sm[(BB) + bD2]);           \
  } while (0)

  // fragment read bases (halves, loop-invariant; hs selects kchunk 0/1)
  const int aI = (hs * 128 + wvr * 64 + l31) * 8;
  const int bI = (hs * 192 + wvc * 96 + l31) * 8;

  // prologue: 2-deep prefetch
  ISSUE(0, 0);
  ISSUE(10240, 2 * CH8);

  int bufC = 0, bufP = 20480;
  for (int ks = 0; ks < NS; ++ks) {
    if (ks < NS - 1) {
      asm volatile("s_waitcnt vmcnt(5)" ::: "memory");  // stage ks complete
    } else {
      asm volatile("s_waitcnt vmcnt(0)" ::: "memory");
    }
    asm volatile("s_barrier" ::: "memory");  // everyone's stage ks in LDS

    if (ks + 2 < NS) ISSUE(bufP, (size_t)(ks + 2) * 2 * CH8);

    // compute on bufC: 10 ds_read_b128 + 18 MFMA (no trailing sync)
    half8 ah[2], al[2], bh[3], bl[3];
#pragma unroll
    for (int rf = 0; rf < 2; ++rf) {
      ah[rf] = *(const half8*)&sm[bufC + aI + rf * 256];
      al[rf] = *(const half8*)&sm[bufC + 2048 + aI + rf * 256];
    }
#pragma unroll
    for (int cf = 0; cf < 3; ++cf) {
      bh[cf] = *(const half8*)&sm[bufC + 4096 + bI + cf * 256];
      bl[cf] = *(const half8*)&sm[bufC + 7168 + bI + cf * 256];
    }
    // term-major: same acc reused every 6 MFMAs (pipe-latency safe); per-acc
    // order matches R2: chunk pair ascending, terms hh, hl, lh.
#pragma unroll
    for (int rf = 0; rf < 2; ++rf)
#pragma unroll
      for (int cf = 0; cf < 3; ++cf)
        acc[rf][cf] = MFMA_(ah[rf], bh[cf], acc[rf][cf]);
#pragma unroll
    for (int rf = 0; rf < 2; ++rf)
#pragma unroll
      for (int cf = 0; cf < 3; ++cf)
        acc[rf][cf] = MFMA_(ah[rf], bl[cf], acc[rf][cf]);
#pragma unroll
    for (int rf = 0; rf < 2; ++rf)
#pragma unroll
      for (int cf = 0; cf < 3; ++cf)
        acc[rf][cf] = MFMA_(al[rf], bh[cf], acc[rf][cf]);

    bufC = (bufC == 20480) ? 0 : bufC + 10240;
    bufP = (bufP == 20480) ? 0 : bufP + 10240;
  }

  // Epilogue: v[i,j] = rsqrt(img_ss[i]) * D[i,j]; column max+argmax
  // (first-index wins). 32x32 C/D: col=lane&31, row=(reg&3)+8*(reg>>2)+4*hs.
  float nrv[2][16];
#pragma unroll
  for (int rf = 0; rf < 2; ++rf) {
    const int base_i = row0 + wvr * 64 + rf * 32 + 4 * hs;
#pragma unroll
    for (int g2 = 0; g2 < 4; ++g2) {
      const floatx4 s4 = *(const floatx4*)&img_ss[base_i + 8 * g2];
#pragma unroll
      for (int r2 = 0; r2 < 4; ++r2) nrv[rf][g2 * 4 + r2] = 1.0f / sqrtf(s4[r2]);
    }
  }
#pragma unroll
  for (int cf = 0; cf < 3; ++cf) {
    const int j = col0 + wvc * 96 + cf * 32 + l31;
    float best = -3.4e38f;
    int bi = 0x7FFFFFFF;
#pragma unroll
    for (int rf = 0; rf < 2; ++rf) {
      const int base_i = row0 + wvr * 64 + rf * 32 + 4 * hs;
#pragma unroll
      for (int g2 = 0; g2 < 4; ++g2)
#pragma unroll
        for (int r2 = 0; r2 < 4; ++r2) {
          const int i = base_i + 8 * g2 + r2;
          const float v = acc[rf][cf][g2 * 4 + r2] * nrv[rf][g2 * 4 + r2];
          if (v > best) { best = v; bi = i; }  // ascending i => first wins
        }
    }
    const float ov = __shfl_xor(best, 32, 64);
    const int oi = __shfl_xor(bi, 32, 64);
    if (ov > best || (ov == best && oi < bi)) { best = ov; bi = oi; }
    if (hs == 0) {
      const unsigned u = __float_as_uint(best);
      const unsigned key = (u & 0x80000000u) ? ~u : (u | 0x80000000u);
      const unsigned long long pk =
          ((unsigned long long)key << 32) | (unsigned)(~(unsigned)bi);
      atomicMax(&packed[j], pk);
    }
  }
}

// ---------------------------------------------------------------------------
// Pass 3: decode packed, apply rsqrt(sty_ss[j]); out[0..A)=nearest,
// out[A..2A)=max_sim.
// ---------------------------------------------------------------------------
__global__ __launch_bounds__(256) void finalize_kernel(
    const unsigned long long* __restrict__ packed,
    const float* __restrict__ sty_ss, float* __restrict__ out) {
  const int j = blockIdx.x * 256 + threadIdx.x;
  if (j >= A_DIM) return;
  const unsigned long long p = packed[j];
  const unsigned key = (unsigned)(p >> 32);
  const unsigned u = (key & 0x80000000u) ? (key ^ 0x80000000u) : ~key;
  const float v = __uint_as_float(u);
  const int idx = (int)(~(unsigned)(p & 0xFFFFFFFFu));
  out[j] = (float)idx;
  out[A_DIM + j] = v * (1.0f / sqrtf(sty_ss[j]));
}

extern "C" void kernel_launch(void* const* d_in, const int* in_sizes, int n_in,
                              void* d_out, int out_size, void* d_ws, size_t ws_size,
                              hipStream_t stream) {
  const float* model = (const float*)d_in[0];  // img side
  const float* style = (const float*)d_in[1];  // sty side
  float* out = (float*)d_out;
  char* ws = (char*)d_ws;

  const size_t usz = (size_t)A_DIM * L_DIM * 2;  // one f16 matrix: 37,748,736 B
  _Float16* img_hi = (_Float16*)(ws);
  _Float16* img_lo = (_Float16*)(ws + usz);
  _Float16* sty_hi = (_Float16*)(ws + 2 * usz);
  _Float16* sty_lo = (_Float16*)(ws + 3 * usz);
  float* img_ss = (float*)(ws + 4 * usz);        // zeroed accumulators
  float* sty_ss = img_ss + A_DIM;
  unsigned long long* packed = (unsigned long long*)(img_ss + 2 * A_DIM);

  // zero ss accumulators (2*A*4 B) + packed (A*8 B) in one contiguous memset
  hipMemsetAsync(img_ss, 0, (size_t)A_DIM * 16, stream);
  prep_kernel<<<dim3(CH / CPB, H_DIM / 3, 2), 256, 0, stream>>>(
      model, style, img_hi, img_lo, sty_hi, sty_lo, img_ss, sty_ss);
  gemm_max_kernel<<<dim3((A_DIM / BM) * (A_DIM / BN)), 256, 0, stream>>>(
      sty_hi, sty_lo, img_hi, img_lo, img_ss, packed);
  finalize_kernel<<<18, 256, 0, stream>>>(packed, sty_ss, out);
}